// Round 11
// baseline (3689.565 us; speedup 1.0000x reference)
//
#include <hip/hip_runtime.h>

// DeepHandwritingPredictionModel: 3-layer peephole LSTM (B=64,T=800,U=400) + MDN(M=20)
// Round 11 = Round 10 (XCD clustering, 1 block/CU) + counter-driven LDS fixes:
//  - permuted Z layout: z-col j at slot (j&7)*40+j/8 -> epilogue reads are
//    lane-stride-1 (conflict-free); writes <=2-way (free).
//  - rec: B3 removed (B1/B2 provide all orderings) -> 2 barriers/step.
//  - pre: Zp[2] double buffer -> 3 barriers/chunk (was 6).

#define TSTEPS 800
#define NG 4            // batch groups
#define GB 16           // batches per group
#define NSL 5           // slices / splits per (layer,group)
#define UB 80           // units per slice
#define CB 320          // cols per slice (4 gates * UB)
#define KP 416          // padded K (400 h | 3 x | 1 one | pad)
#define RD 16           // hring / zin ring depth
#define HXD 4           // tagged hx ring depth
#define AS 424          // A LDS stride (bf16)
#define ZS 332          // Z LDS stride (f32)

typedef __attribute__((ext_vector_type(8))) __bf16 bf16x8;
typedef __attribute__((ext_vector_type(4))) float floatx4;

struct Peeps { const float* pi[3]; const float* pf[3]; const float* po[3]; };

__device__ __forceinline__ unsigned short f2bf(float f) {
    unsigned int u = __float_as_uint(f);
    return (unsigned short)((u + 0x7FFFu + ((u >> 16) & 1u)) >> 16);
}
__device__ __forceinline__ float bf_lo(unsigned u) { return __uint_as_float(u << 16); }
__device__ __forceinline__ float bf_hi(unsigned u) { return __uint_as_float(u & 0xFFFF0000u); }
__device__ __forceinline__ float sigm_(float v) { return 1.f / (1.f + __expf(-v)); }
__device__ __forceinline__ float tanh_(float v) { float e = __expf(2.f * v); return 1.f - 2.f / (e + 1.f); }
__device__ __forceinline__ unsigned ld_a(const unsigned* p) {
    return __hip_atomic_load(p, __ATOMIC_RELAXED, __HIP_MEMORY_SCOPE_AGENT);
}
__device__ __forceinline__ void st_a(unsigned* p, unsigned v) {
    __hip_atomic_store(p, v, __ATOMIC_RELAXED, __HIP_MEMORY_SCOPE_AGENT);
}

// ---- weight packing ------------------------------------------------------
__global__ void pack_rec(const float* __restrict__ Wx, const float* __restrict__ Wh,
                         const float* __restrict__ bias, unsigned short* __restrict__ dst,
                         int is_l0) {
    int idx = blockIdx.x * 256 + threadIdx.x;
    if (idx >= 1600 * KP) return;
    int col = idx / KP, k = idx - col * KP;
    int co = (col & 3) * 400 + (col >> 2);
    float v = 0.f;
    if (k < 400) v = Wh[k * 1600 + co];
    else if (is_l0) {
        if (k < 403) v = Wx[(k - 400) * 1600 + co];
        else if (k == 403) v = bias[co];
    }
    dst[idx] = f2bf(v);
}
__global__ void pack_pre(const float* __restrict__ Wx, const float* __restrict__ bias,
                         unsigned short* __restrict__ dst) {
    int idx = blockIdx.x * 256 + threadIdx.x;
    if (idx >= 1600 * KP) return;
    int col = idx / KP, k = idx - col * KP;
    int co = (col & 3) * 400 + (col >> 2);
    float v = 0.f;
    if (k < 400) v = Wx[(3 + k) * 1600 + co];
    else if (k < 403) v = Wx[(k - 400) * 1600 + co];
    else if (k == 403) v = bias[co];
    dst[idx] = f2bf(v);
}
__global__ void pack_x(const float* __restrict__ x, unsigned short* __restrict__ xp) {
    int idx = blockIdx.x * 256 + threadIdx.x;   // idx = t*64 + b
    if (idx >= TSTEPS * 64) return;
    int t = idx / 64, b = idx - t * 64;
    unsigned short o[4];
    for (int d = 0; d < 3; ++d) o[d] = f2bf(x[(b * TSTEPS + t) * 3 + d]);
    o[3] = 0x3F80u;
    *(uint2*)(xp + (size_t)idx * 4) = *(uint2*)o;
}
__global__ void pack_mdn(const float* __restrict__ Wm, const float* __restrict__ bm,
                         unsigned short* __restrict__ dst) {
    int idx = blockIdx.x * 256 + threadIdx.x;
    if (idx >= 128 * KP) return;
    int col = idx / KP, k = idx - col * KP;
    float v = 0.f;
    if (col < 121) {
        if (k < 400) v = Wm[k * 121 + col];
        else if (k == 400) v = bm[col];
    }
    dst[idx] = f2bf(v);
}

// ---- fused pipeline ------------------------------------------------------
// Grid 120: xcd=bid&7, slot=bid>>3 (r9-validated bid%8->XCD round-robin).
//   xcd g in 0..3 : slots 0-4 rec(l=0,g), 5-9 rec(l=2,g), 10-14 pre(lz=1,g)
//   xcd 4+g       : slots 0-4 rec(l=1,g), 5-9 pre(lz=0,g), 10-14 idle
// hx   : [3][NG][HXD][16][400] u32 tagged (t<<16|bf16), slot t&3
// hring: [3][NG][RD][16][200] u32 packed 2xbf16, slot t&15 (for pre)
// zin  : [2][NG][RD][16][800] u32 packed 2xbf16, slot t&15
// seqb : FH[(l*NG+g)*NSL+s]*16 ; FZ at +60*16: [(lz*NG+g)*NSL+sp]*16
// Z LDS permutation: z-col j stored at slot (j&7)*40 + (j>>3) within its row.
__global__ __launch_bounds__(640)
void fused_scan(const unsigned short* __restrict__ Bp,
                const unsigned short* __restrict__ Bpre,
                const unsigned short* __restrict__ xpack,
                unsigned* __restrict__ hx,
                unsigned* __restrict__ hring,
                unsigned* __restrict__ zin,
                unsigned* __restrict__ seqb,
                unsigned* __restrict__ h2,      // [T][64][200] dwords (2xbf16)
                Peeps pp) {
    const int tid = threadIdx.x;
    const int lane = tid & 63;
    const int w = tid >> 6;
    const int bid = blockIdx.x;

    const int xcd = bid & 7;
    const int slot = bid >> 3;        // 0..14
    int g, rl = -1, rs = 0, plz = -1, psp = 0;
    if (xcd < 4) {
        g = xcd;
        if (slot < 5)       { rl = 0; rs = slot; }
        else if (slot < 10) { rl = 2; rs = slot - 5; }
        else                { plz = 1; psp = slot - 10; }
    } else {
        g = xcd - 4;
        if (slot < 5)       { rl = 1; rs = slot; }
        else if (slot < 10) { plz = 0; psp = slot - 5; }
        else return;
    }

    __shared__ unsigned short A[32 * AS];
    __shared__ float Z[2 * 16 * ZS];   // rec uses [0]; pre uses both halves

    for (int i = tid; i < 32 * AS; i += 640) A[i] = 0;

    const int er = tid / 40;          // batch row 0..15
    const int up = tid - er * 40;     // unit-pair 0..39
    const int cc = lane & 15;
    const int aoff = cc * AS + ((lane >> 4) << 3);
    const int zr = (lane >> 4) << 2;
    // permuted Z write slot for col zc0=w*32+cc (and zc0+16 -> slotA+2)
    const int slotA = (cc & 7) * 40 + w * 4 + (cc >> 3);

    if (rl >= 0) {
        // ---------------- recurrence block ----------------
        const int l = rl;
        const int s = rs;
        bf16x8 breg[2][13];
        #pragma unroll
        for (int n = 0; n < 2; ++n) {
            const unsigned short* bpp = Bp + (size_t)l * 1600 * KP
                + (size_t)(s * CB + w * 32 + n * 16 + cc) * KP + ((lane >> 4) << 3);
            #pragma unroll
            for (int kt = 0; kt < 13; ++kt) breg[n][kt] = *(const bf16x8*)(bpp + kt * 32);
        }
        unsigned* hxL = hx + (size_t)(l * NG + g) * HXD * 6400;
        unsigned* ringL = hring + (size_t)(l * NG + g) * RD * 3200;
        const unsigned* zinL = zin + (size_t)((l - 1) * NG + g) * RD * 12800;
        unsigned* FHown = seqb + ((l * NG + g) * NSL + s) * 16;
        const unsigned* FZup = seqb + (60 + ((l - 1) * NG + g) * NSL) * 16;
        const unsigned* FZdn = seqb + (60 + (l * NG + g) * NSL) * 16;

        const int p0 = ((s + 1) % 5) * 80, p1 = ((s + 2) % 5) * 80;
        const int p2 = ((s + 3) % 5) * 80, p3 = ((s + 4) % 5) * 80;
        const int ug0 = s * UB + 2 * up;
        const float pi0 = pp.pi[l][ug0], pi1 = pp.pi[l][ug0 + 1];
        const float pf0 = pp.pf[l][ug0], pf1 = pp.pf[l][ug0 + 1];
        const float po0 = pp.po[l][ug0], po1 = pp.po[l][ug0 + 1];
        float c0 = 0.f, c1 = 0.f;

        __syncthreads();
        if (l == 0 && tid < 16)
            *(uint2*)(&A[tid * AS + 400]) = *(const uint2*)(xpack + ((size_t)0 * 64 + g * 16 + tid) * 4);
        __syncthreads();

        for (int t = 0; t < TSTEPS; ++t) {
            // ---- detect: poll peers' tagged h(t-1) + amortized flag gates ----
            {
                const unsigned want = (unsigned)(t - 1) << 16;
                const unsigned* hb = hxL + (size_t)((t + 3) & 3) * 6400 + er * 400 + 2 * up;
                const unsigned* fp = nullptr; unsigned fneed = 0;
                if (l > 0 && (t & 3) == 0 && tid < NSL) { fp = FZup + tid * 16; fneed = (unsigned)(t + 4); }
                else if (l < 2 && (t & 7) == 0 && tid >= NSL && tid < 2 * NSL) {
                    fp = FZdn + (tid - NSL) * 16; fneed = (unsigned)(t > 8 ? t - 8 : 0);
                }
                unsigned v0, v1, v2, v3, v4, v5, v6, v7;
                for (;;) {
                    bool ok = true;
                    if (t > 0) {
                        v0 = ld_a(hb + p0); v1 = ld_a(hb + p0 + 1);
                        v2 = ld_a(hb + p1); v3 = ld_a(hb + p1 + 1);
                        v4 = ld_a(hb + p2); v5 = ld_a(hb + p2 + 1);
                        v6 = ld_a(hb + p3); v7 = ld_a(hb + p3 + 1);
                        ok = ((v0 & 0xFFFF0000u) == want) & ((v1 & 0xFFFF0000u) == want) &
                             ((v2 & 0xFFFF0000u) == want) & ((v3 & 0xFFFF0000u) == want) &
                             ((v4 & 0xFFFF0000u) == want) & ((v5 & 0xFFFF0000u) == want) &
                             ((v6 & 0xFFFF0000u) == want) & ((v7 & 0xFFFF0000u) == want);
                    }
                    if (fp) ok &= (ld_a(fp) >= fneed);
                    if (__all(ok)) break;
                }
                if (t > 0) {
                    const int ab = er * AS + 2 * up;
                    *(unsigned*)&A[ab + p0] = (v0 & 0xFFFFu) | (v1 << 16);
                    *(unsigned*)&A[ab + p1] = (v2 & 0xFFFFu) | (v3 << 16);
                    *(unsigned*)&A[ab + p2] = (v4 & 0xFFFFu) | (v5 << 16);
                    *(unsigned*)&A[ab + p3] = (v6 & 0xFFFFu) | (v7 << 16);
                }
            }
            __syncthreads();                       // B1 (drains t-1's global stores)
            if (tid == 0) st_a(FHown, (unsigned)t);   // h(0..t-1) now visible

            unsigned q0, q1, q2, q3;
            if (l > 0) {                           // zin(t) into regs; consumed after B2
                const unsigned* zp = zinL + (size_t)(t & 15) * 12800 + er * 800 + 4 * (s * 40 + up);
                q0 = ld_a(zp); q1 = ld_a(zp + 1); q2 = ld_a(zp + 2); q3 = ld_a(zp + 3);
            }

            floatx4 a0 = {0, 0, 0, 0}, a1 = {0, 0, 0, 0};
            #pragma unroll
            for (int kt = 0; kt < 13; ++kt) {
                bf16x8 a = *(const bf16x8*)(&A[aoff + kt * 32]);
                a0 = __builtin_amdgcn_mfma_f32_16x16x32_bf16(a, breg[0][kt], a0, 0, 0, 0);
                a1 = __builtin_amdgcn_mfma_f32_16x16x32_bf16(a, breg[1][kt], a1, 0, 0, 0);
            }
            #pragma unroll
            for (int ri = 0; ri < 4; ++ri) {       // permuted Z write (<=2-way banks)
                Z[(zr + ri) * ZS + slotA] = a0[ri];
                Z[(zr + ri) * ZS + slotA + 2] = a1[ri];
            }
            __syncthreads();                       // B2

            float zv[8];
            #pragma unroll
            for (int k = 0; k < 8; ++k)            // lane-stride-1: conflict-free
                zv[k] = Z[er * ZS + 40 * k + up];
            float4 za = {zv[0], zv[1], zv[2], zv[3]};
            float4 zb4 = {zv[4], zv[5], zv[6], zv[7]};
            if (l > 0) {
                za.x += bf_lo(q0); za.y += bf_hi(q0); za.z += bf_lo(q1); za.w += bf_hi(q1);
                zb4.x += bf_lo(q2); zb4.y += bf_hi(q2); zb4.z += bf_lo(q3); zb4.w += bf_hi(q3);
            }
            float iv = sigm_(za.x + pi0 * c0);
            float fv = sigm_(za.y + pf0 * c0);
            float cn = fv * c0 + iv * tanh_(za.z);
            float ov = sigm_(za.w + po0 * cn);
            float h0 = ov * tanh_(cn);
            c0 = cn;
            iv = sigm_(zb4.x + pi1 * c1);
            fv = sigm_(zb4.y + pf1 * c1);
            cn = fv * c1 + iv * tanh_(zb4.z);
            ov = sigm_(zb4.w + po1 * cn);
            float h1 = ov * tanh_(cn);
            c1 = cn;
            unsigned packh = (unsigned)f2bf(h0) | ((unsigned)f2bf(h1) << 16);
            *(unsigned*)&A[er * AS + ug0] = packh;            // own h(t) -> LDS
            if (l == 0 && tid < 16 && t + 1 < TSTEPS)
                *(uint2*)(&A[tid * AS + 400]) = *(const uint2*)(xpack + ((size_t)(t + 1) * 64 + g * 16 + tid) * 4);
            // (B3 removed: B1/B2 already order A and Z accesses across steps)

            // global stores: drain overlaps the next detect spin
            unsigned* hxs = hxL + (size_t)(t & 3) * 6400 + er * 400 + ug0;
            st_a(hxs, ((unsigned)t << 16) | (packh & 0xFFFFu));
            st_a(hxs + 1, ((unsigned)t << 16) | (packh >> 16));
            if (l < 2)
                st_a(ringL + (size_t)(t & 15) * 3200 + er * 200 + s * 40 + up, packh);
            else
                h2[(size_t)t * 12800 + (g * GB + er) * 200 + s * 40 + up] = packh;
        }
        __syncthreads();
        if (tid == 0) st_a(FHown, (unsigned)TSTEPS);
    } else {
        // ---------------- preGEMM block (TCH=2 steps per iter) ----------------
        const int lz = plz;                  // feeds layer lz+1
        const int sp = psp;
        bf16x8 breg[2][13];
        #pragma unroll
        for (int n = 0; n < 2; ++n) {
            const unsigned short* bpp = Bpre + (size_t)lz * 1600 * KP
                + (size_t)(sp * CB + w * 32 + n * 16 + cc) * KP + ((lane >> 4) << 3);
            #pragma unroll
            for (int kt = 0; kt < 13; ++kt) breg[n][kt] = *(const bf16x8*)(bpp + kt * 32);
        }
        const unsigned* ringS = hring + (size_t)(lz * NG + g) * RD * 3200;
        unsigned* zinD = zin + (size_t)(lz * NG + g) * RD * 12800;
        const unsigned* FHup = seqb + ((lz * NG + g) * NSL) * 16;
        const unsigned* FHdn = seqb + (((lz + 1) * NG + g) * NSL) * 16;
        unsigned* FZown = seqb + (60 + (lz * NG + g) * NSL + sp) * 16;
        __syncthreads();

        for (int c = 0; c < TSTEPS; c += 2) {
            {   // ballot poll: h availability + zin-ring backpressure
                const unsigned* fp = nullptr; unsigned need = 0;
                if (tid < NSL) { fp = FHup + tid * 16; need = (unsigned)(c + 2); }
                else if (tid < 2 * NSL) { fp = FHdn + (tid - NSL) * 16; need = (unsigned)(c > 14 ? c - 14 : 0); }
                bool ok = (fp == nullptr) || (ld_a(fp) >= need);
                while (!__all(ok)) { if (!ok) ok = ld_a(fp) >= need; }
            }
            __syncthreads();                       // B1 (drains prev chunk's zin stores)
            if (tid == 0 && c > 0) st_a(FZown, (unsigned)c);   // zin(0..c-1) visible

            for (int i = tid; i < 6400; i += 640) {   // stage h(c),h(c+1)
                int tc = (i >= 3200) ? 1 : 0;
                int j = i - tc * 3200;
                unsigned v = ld_a(ringS + (size_t)((c + tc) & 15) * 3200 + j);
                int r = j / 200, d = j - r * 200;
                *(unsigned*)&A[(tc * 16 + r) * AS + 2 * d] = v;
            }
            if (tid < 32) {
                int tc = tid >> 4, r = tid & 15;
                *(uint2*)(&A[(tc * 16 + r) * AS + 400]) =
                    *(const uint2*)(xpack + ((size_t)(c + tc) * 64 + g * 16 + r) * 4);
            }
            __syncthreads();                       // B2

            floatx4 a00 = {0,0,0,0}, a01 = {0,0,0,0}, a10 = {0,0,0,0}, a11 = {0,0,0,0};
            #pragma unroll
            for (int kt = 0; kt < 13; ++kt) {
                bf16x8 x0 = *(const bf16x8*)(&A[aoff + kt * 32]);
                bf16x8 x1 = *(const bf16x8*)(&A[aoff + 16 * AS + kt * 32]);
                a00 = __builtin_amdgcn_mfma_f32_16x16x32_bf16(x0, breg[0][kt], a00, 0, 0, 0);
                a01 = __builtin_amdgcn_mfma_f32_16x16x32_bf16(x0, breg[1][kt], a01, 0, 0, 0);
                a10 = __builtin_amdgcn_mfma_f32_16x16x32_bf16(x1, breg[0][kt], a10, 0, 0, 0);
                a11 = __builtin_amdgcn_mfma_f32_16x16x32_bf16(x1, breg[1][kt], a11, 0, 0, 0);
            }
            #pragma unroll
            for (int ri = 0; ri < 4; ++ri) {       // both steps into Zp[0]/Zp[1]
                Z[(zr + ri) * ZS + slotA] = a00[ri];
                Z[(zr + ri) * ZS + slotA + 2] = a01[ri];
                Z[16 * ZS + (zr + ri) * ZS + slotA] = a10[ri];
                Z[16 * ZS + (zr + ri) * ZS + slotA + 2] = a11[ri];
            }
            __syncthreads();                       // B3 (single Z-ready barrier)

            float zv0[8], zv1[8];
            #pragma unroll
            for (int k = 0; k < 8; ++k) {
                zv0[k] = Z[er * ZS + 40 * k + up];
                zv1[k] = Z[16 * ZS + er * ZS + 40 * k + up];
            }
            unsigned* zg0 = zinD + (size_t)(c & 15) * 12800 + er * 800 + sp * 160 + 4 * up;
            unsigned* zg1 = zinD + (size_t)((c + 1) & 15) * 12800 + er * 800 + sp * 160 + 4 * up;
            st_a(zg0,     (unsigned)f2bf(zv0[0]) | ((unsigned)f2bf(zv0[1]) << 16));
            st_a(zg0 + 1, (unsigned)f2bf(zv0[2]) | ((unsigned)f2bf(zv0[3]) << 16));
            st_a(zg0 + 2, (unsigned)f2bf(zv0[4]) | ((unsigned)f2bf(zv0[5]) << 16));
            st_a(zg0 + 3, (unsigned)f2bf(zv0[6]) | ((unsigned)f2bf(zv0[7]) << 16));
            st_a(zg1,     (unsigned)f2bf(zv1[0]) | ((unsigned)f2bf(zv1[1]) << 16));
            st_a(zg1 + 1, (unsigned)f2bf(zv1[2]) | ((unsigned)f2bf(zv1[3]) << 16));
            st_a(zg1 + 2, (unsigned)f2bf(zv1[4]) | ((unsigned)f2bf(zv1[5]) << 16));
            st_a(zg1 + 3, (unsigned)f2bf(zv1[6]) | ((unsigned)f2bf(zv1[7]) << 16));
            // (trailing barrier removed: next chunk's B1/B2 order Z reuse)
        }
        __syncthreads();
        if (tid == 0) st_a(FZown, (unsigned)TSTEPS);
    }
}

// ---- MDN head ------------------------------------------------------------
__global__ __launch_bounds__(256)
void mdn_kernel(const unsigned short* __restrict__ h2,
                const unsigned short* __restrict__ Bm,
                float* __restrict__ out) {
    const int blk = blockIdx.x;
    const int b = blk / 25;
    const int t0 = (blk - b * 25) * 32;
    const int tid = threadIdx.x;
    const int lane = tid & 63;
    const int w = tid >> 6;
    const int m = w & 1, nh = w >> 1;

    __shared__ unsigned short A[32 * 424];
    __shared__ float Z[32 * 132];
    __shared__ float rmax[32], rinv[32];

    for (int i = tid; i < 32 * 424; i += 256) A[i] = 0;
    __syncthreads();
    for (int c = tid; c < 32 * 50; c += 256) {
        int r = c / 50, j = c - r * 50;
        *(bf16x8*)(&A[r * 424 + j * 8]) = *(const bf16x8*)(h2 + (size_t)(t0 + r) * 25600 + b * 400 + j * 8);
    }
    if (tid < 32) A[tid * 424 + 400] = 0x3F80u;
    __syncthreads();

    floatx4 acc[4] = {{0,0,0,0},{0,0,0,0},{0,0,0,0},{0,0,0,0}};
    const int aoff = (m * 16 + (lane & 15)) * 424 + ((lane >> 4) << 3);
    #pragma unroll
    for (int kt = 0; kt < 13; ++kt) {
        bf16x8 a = *(const bf16x8*)(&A[aoff + kt * 32]);
        #pragma unroll
        for (int n = 0; n < 4; ++n) {
            const unsigned short* bp = Bm + (size_t)((nh * 4 + n) * 16 + (lane & 15)) * KP
                                          + ((lane >> 4) << 3) + kt * 32;
            acc[n] = __builtin_amdgcn_mfma_f32_16x16x32_bf16(a, *(const bf16x8*)bp, acc[n], 0, 0, 0);
        }
    }
    #pragma unroll
    for (int n = 0; n < 4; ++n) {
        int zc = (nh * 4 + n) * 16 + (lane & 15);
        int zrow = m * 16 + ((lane >> 4) << 2);
        #pragma unroll
        for (int ri = 0; ri < 4; ++ri)
            Z[(zrow + ri) * 132 + zc] = acc[n][ri];
    }
    __syncthreads();
    if (tid < 32) {
        float mx = -1e30f;
        for (int j = 0; j < 20; ++j) mx = fmaxf(mx, Z[tid * 132 + j]);
        float sm = 0.f;
        for (int j = 0; j < 20; ++j) sm += __expf(Z[tid * 132 + j] - mx);
        rmax[tid] = mx;
        rinv[tid] = 1.f / sm;
    }
    __syncthreads();
    for (int idxo = tid; idxo < 32 * 121; idxo += 256) {
        int r = idxo / 121, jo = idxo - r * 121;
        float v = Z[r * 132 + jo];
        float o;
        if (jo < 20) o = __expf(v - rmax[r]) * rinv[r];
        else if (jo < 60) o = v;
        else if (jo < 100) o = __expf(v);
        else if (jo < 120) o = tanh_(v);
        else o = sigm_(v);
        out[(size_t)(b * TSTEPS + t0 + r) * 121 + jo] = o;
    }
}

extern "C" void kernel_launch(void* const* d_in, const int* in_sizes, int n_in,
                              void* d_out, int out_size, void* d_ws, size_t ws_size,
                              hipStream_t stream) {
    const float* x = (const float*)d_in[0];
    const float* Wx[3] = {(const float*)d_in[1], (const float*)d_in[7], (const float*)d_in[13]};
    const float* Wh[3] = {(const float*)d_in[2], (const float*)d_in[8], (const float*)d_in[14]};
    const float* bb[3] = {(const float*)d_in[3], (const float*)d_in[9], (const float*)d_in[15]};
    Peeps pp;
    for (int l = 0; l < 3; ++l) {
        pp.pi[l] = (const float*)d_in[4 + 6 * l];
        pp.pf[l] = (const float*)d_in[5 + 6 * l];
        pp.po[l] = (const float*)d_in[6 + 6 * l];
    }
    const float* Wm = (const float*)d_in[19];
    const float* bm = (const float*)d_in[20];
    float* out = (float*)d_out;

    char* base = (char*)d_ws;
    size_t off = 0;
    auto alloc = [&](size_t bytes) -> void* {
        void* r = base + off;
        off = (off + bytes + 255) & ~(size_t)255;
        return r;
    };
    unsigned* seqb        = (unsigned*)alloc(1600 * sizeof(unsigned));              // 6.4 KB
    unsigned* hx          = (unsigned*)alloc((size_t)3 * NG * HXD * 6400 * 4);      // 1.23 MB
    unsigned* hring       = (unsigned*)alloc((size_t)3 * NG * RD * 3200 * 4);       // 2.46 MB
    unsigned* zin         = (unsigned*)alloc((size_t)2 * NG * RD * 12800 * 4);      // 6.55 MB
    unsigned short* Bp    = (unsigned short*)alloc((size_t)3 * 1600 * KP * 2);      // 4.0 MB
    unsigned short* Bpre  = (unsigned short*)alloc((size_t)2 * 1600 * KP * 2);      // 2.7 MB
    unsigned short* Bm    = (unsigned short*)alloc((size_t)128 * KP * 2);
    unsigned short* xpk   = (unsigned short*)alloc((size_t)TSTEPS * 64 * 4 * 2);
    unsigned short* h2    = (unsigned short*)alloc((size_t)TSTEPS * 64 * 400 * 2);  // 41 MB

    hipMemsetAsync(seqb, 0, 1600 * sizeof(unsigned), stream);
    hipMemsetAsync(hx, 0xAA, (size_t)3 * NG * HXD * 6400 * 4, stream);  // tags can't alias

    for (int l = 0; l < 3; ++l)
        pack_rec<<<2600, 256, 0, stream>>>(Wx[l], Wh[l], bb[l], Bp + (size_t)l * 1600 * KP, l == 0);
    pack_pre<<<2600, 256, 0, stream>>>(Wx[1], bb[1], Bpre);
    pack_pre<<<2600, 256, 0, stream>>>(Wx[2], bb[2], Bpre + (size_t)1600 * KP);
    pack_x<<<200, 256, 0, stream>>>(x, xpk);
    pack_mdn<<<208, 256, 0, stream>>>(Wm, bm, Bm);

    fused_scan<<<120, 640, 0, stream>>>(Bp, Bpre, xpk, hx, hring, zin, seqb,
                                        (unsigned*)h2, pp);

    mdn_kernel<<<1600, 256, 0, stream>>>(h2, Bm, out);
}

// Round 12
// 3242.602 us; speedup vs baseline: 1.1378x; 1.1378x over previous
//
#include <hip/hip_runtime.h>

// DeepHandwritingPredictionModel: 3-layer peephole LSTM (B=64,T=800,U=400) + MDN(M=20)
// Round 12 = Round 10 body (best, 3037us) + pre chunk-parity doubling:
//   2 sets of pre blocks per (lz,g): even set chunks c%4==0, odd set c%4==2,
//   each strides 4 steps/iter -> pre per-set rate halved (pre was implicated as
//   the pipeline pacer by r7's 3.7x slowdown when pre work was doubled).
//   Grid 160: xcd=bid&7, slot=bid>>3 in 0..19.
//   xcd g in 0..3 : s0-4 rec(l=0), s5-9 rec(l=2), s10-14 preE(lz=1), s15-19 preO(lz=1)
//   xcd 4+g       : s0-4 rec(l=1), s5-9 preE(lz=0), s10-14 preO(lz=0), s15-19 idle

#define TSTEPS 800
#define NG 4
#define GB 16
#define NSL 5
#define UB 80
#define CB 320
#define KP 416
#define RD 16
#define HXD 4
#define AS 424
#define ZS 332

typedef __attribute__((ext_vector_type(8))) __bf16 bf16x8;
typedef __attribute__((ext_vector_type(4))) float floatx4;

struct Peeps { const float* pi[3]; const float* pf[3]; const float* po[3]; };

__device__ __forceinline__ unsigned short f2bf(float f) {
    unsigned int u = __float_as_uint(f);
    return (unsigned short)((u + 0x7FFFu + ((u >> 16) & 1u)) >> 16);
}
__device__ __forceinline__ float bf_lo(unsigned u) { return __uint_as_float(u << 16); }
__device__ __forceinline__ float bf_hi(unsigned u) { return __uint_as_float(u & 0xFFFF0000u); }
__device__ __forceinline__ float sigm_(float v) { return 1.f / (1.f + __expf(-v)); }
__device__ __forceinline__ float tanh_(float v) { float e = __expf(2.f * v); return 1.f - 2.f / (e + 1.f); }
__device__ __forceinline__ unsigned ld_a(const unsigned* p) {
    return __hip_atomic_load(p, __ATOMIC_RELAXED, __HIP_MEMORY_SCOPE_AGENT);
}
__device__ __forceinline__ void st_a(unsigned* p, unsigned v) {
    __hip_atomic_store(p, v, __ATOMIC_RELAXED, __HIP_MEMORY_SCOPE_AGENT);
}

// ---- weight packing ------------------------------------------------------
__global__ void pack_rec(const float* __restrict__ Wx, const float* __restrict__ Wh,
                         const float* __restrict__ bias, unsigned short* __restrict__ dst,
                         int is_l0) {
    int idx = blockIdx.x * 256 + threadIdx.x;
    if (idx >= 1600 * KP) return;
    int col = idx / KP, k = idx - col * KP;
    int co = (col & 3) * 400 + (col >> 2);
    float v = 0.f;
    if (k < 400) v = Wh[k * 1600 + co];
    else if (is_l0) {
        if (k < 403) v = Wx[(k - 400) * 1600 + co];
        else if (k == 403) v = bias[co];
    }
    dst[idx] = f2bf(v);
}
__global__ void pack_pre(const float* __restrict__ Wx, const float* __restrict__ bias,
                         unsigned short* __restrict__ dst) {
    int idx = blockIdx.x * 256 + threadIdx.x;
    if (idx >= 1600 * KP) return;
    int col = idx / KP, k = idx - col * KP;
    int co = (col & 3) * 400 + (col >> 2);
    float v = 0.f;
    if (k < 400) v = Wx[(3 + k) * 1600 + co];
    else if (k < 403) v = Wx[(k - 400) * 1600 + co];
    else if (k == 403) v = bias[co];
    dst[idx] = f2bf(v);
}
__global__ void pack_x(const float* __restrict__ x, unsigned short* __restrict__ xp) {
    int idx = blockIdx.x * 256 + threadIdx.x;   // idx = t*64 + b
    if (idx >= TSTEPS * 64) return;
    int t = idx / 64, b = idx - t * 64;
    unsigned short o[4];
    for (int d = 0; d < 3; ++d) o[d] = f2bf(x[(b * TSTEPS + t) * 3 + d]);
    o[3] = 0x3F80u;
    *(uint2*)(xp + (size_t)idx * 4) = *(uint2*)o;
}
__global__ void pack_mdn(const float* __restrict__ Wm, const float* __restrict__ bm,
                         unsigned short* __restrict__ dst) {
    int idx = blockIdx.x * 256 + threadIdx.x;
    if (idx >= 128 * KP) return;
    int col = idx / KP, k = idx - col * KP;
    float v = 0.f;
    if (col < 121) {
        if (k < 400) v = Wm[k * 121 + col];
        else if (k == 400) v = bm[col];
    }
    dst[idx] = f2bf(v);
}

// ---- fused pipeline ------------------------------------------------------
// hx   : [3][NG][HXD][16][400] u32 tagged (t<<16|bf16), slot t&3
// hring: [3][NG][RD][16][200] u32 packed 2xbf16, slot t&15
// zin  : [2][NG][RD][16][800] u32 packed 2xbf16, slot t&15 (even/odd chunks
//        write disjoint slot sets)
// seqb : FH[(l*NG+g)*NSL+s]*16 (0..959)
//        FZ[(set*2+lz)*NG+g)*NSL+sp] at (60+idx)*16 (960..2239)
__global__ __launch_bounds__(640)
void fused_scan(const unsigned short* __restrict__ Bp,
                const unsigned short* __restrict__ Bpre,
                const unsigned short* __restrict__ xpack,
                unsigned* __restrict__ hx,
                unsigned* __restrict__ hring,
                unsigned* __restrict__ zin,
                unsigned* __restrict__ seqb,
                unsigned* __restrict__ h2,      // [T][64][200] dwords (2xbf16)
                Peeps pp) {
    const int tid = threadIdx.x;
    const int lane = tid & 63;
    const int w = tid >> 6;
    const int bid = blockIdx.x;

    const int xcd = bid & 7;
    const int slot = bid >> 3;        // 0..19
    int g, rl = -1, rs = 0, plz = -1, psp = 0, par = 0;
    if (xcd < 4) {
        g = xcd;
        if (slot < 5)       { rl = 0; rs = slot; }
        else if (slot < 10) { rl = 2; rs = slot - 5; }
        else if (slot < 15) { plz = 1; psp = slot - 10; par = 0; }
        else                { plz = 1; psp = slot - 15; par = 1; }
    } else {
        g = xcd - 4;
        if (slot < 5)       { rl = 1; rs = slot; }
        else if (slot < 10) { plz = 0; psp = slot - 5; par = 0; }
        else if (slot < 15) { plz = 0; psp = slot - 10; par = 1; }
        else return;
    }

    __shared__ unsigned short A[32 * AS];
    __shared__ float Z[16 * ZS];

    for (int i = tid; i < 32 * AS; i += 640) A[i] = 0;

    const int er = tid / 40;
    const int up = tid - er * 40;
    const int aoff = (lane & 15) * AS + ((lane >> 4) << 3);
    const int zc0 = w * 32 + (lane & 15);
    const int zr = (lane >> 4) << 2;

    if (rl >= 0) {
        // ---------------- recurrence block ----------------
        const int l = rl;
        const int s = rs;
        bf16x8 breg[2][13];
        #pragma unroll
        for (int n = 0; n < 2; ++n) {
            const unsigned short* bpp = Bp + (size_t)l * 1600 * KP
                + (size_t)(s * CB + w * 32 + n * 16 + (lane & 15)) * KP + ((lane >> 4) << 3);
            #pragma unroll
            for (int kt = 0; kt < 13; ++kt) breg[n][kt] = *(const bf16x8*)(bpp + kt * 32);
        }
        unsigned* hxL = hx + (size_t)(l * NG + g) * HXD * 6400;
        unsigned* ringL = hring + (size_t)(l * NG + g) * RD * 3200;
        const unsigned* zinL = zin + (size_t)((l - 1) * NG + g) * RD * 12800;
        unsigned* FHown = seqb + ((l * NG + g) * NSL + s) * 16;
        // FZ bases: set e=0/o=1, consumed layer lz=l-1; produced-for layer lz=l
        const unsigned* FZupE = seqb + (60 + ((0 + (l - 1)) * NG + g) * NSL) * 16;
        const unsigned* FZupO = seqb + (60 + ((2 + (l - 1)) * NG + g) * NSL) * 16;
        const unsigned* FZdnE = seqb + (60 + ((0 + l) * NG + g) * NSL) * 16;
        const unsigned* FZdnO = seqb + (60 + ((2 + l) * NG + g) * NSL) * 16;

        const int p0 = ((s + 1) % 5) * 80, p1 = ((s + 2) % 5) * 80;
        const int p2 = ((s + 3) % 5) * 80, p3 = ((s + 4) % 5) * 80;
        const int ug0 = s * UB + 2 * up;
        const float pi0 = pp.pi[l][ug0], pi1 = pp.pi[l][ug0 + 1];
        const float pf0 = pp.pf[l][ug0], pf1 = pp.pf[l][ug0 + 1];
        const float po0 = pp.po[l][ug0], po1 = pp.po[l][ug0 + 1];
        float c0 = 0.f, c1 = 0.f;

        __syncthreads();
        if (l == 0 && tid < 16)
            *(uint2*)(&A[tid * AS + 400]) = *(const uint2*)(xpack + ((size_t)0 * 64 + g * 16 + tid) * 4);
        __syncthreads();

        for (int t = 0; t < TSTEPS; ++t) {
            // ---- detect: poll peers' tagged h(t-1) + amortized flag gates ----
            {
                const unsigned want = (unsigned)(t - 1) << 16;
                const unsigned* hb = hxL + (size_t)((t + 3) & 3) * 6400 + er * 400 + 2 * up;
                const unsigned* fp = nullptr; unsigned fneed = 0;
                if (l > 0 && (t & 3) == 0 && tid < 2 * NSL) {
                    fp = (tid < NSL) ? (FZupE + tid * 16) : (FZupO + (tid - NSL) * 16);
                    fneed = (unsigned)(t + 4);
                } else if (l < 2 && (t & 7) == 0 && tid >= 2 * NSL && tid < 4 * NSL) {
                    fp = (tid < 3 * NSL) ? (FZdnE + (tid - 2 * NSL) * 16)
                                         : (FZdnO + (tid - 3 * NSL) * 16);
                    fneed = (unsigned)(t > 8 ? t - 8 : 0);
                }
                unsigned v0, v1, v2, v3, v4, v5, v6, v7;
                for (;;) {
                    bool ok = true;
                    if (t > 0) {
                        v0 = ld_a(hb + p0); v1 = ld_a(hb + p0 + 1);
                        v2 = ld_a(hb + p1); v3 = ld_a(hb + p1 + 1);
                        v4 = ld_a(hb + p2); v5 = ld_a(hb + p2 + 1);
                        v6 = ld_a(hb + p3); v7 = ld_a(hb + p3 + 1);
                        ok = ((v0 & 0xFFFF0000u) == want) & ((v1 & 0xFFFF0000u) == want) &
                             ((v2 & 0xFFFF0000u) == want) & ((v3 & 0xFFFF0000u) == want) &
                             ((v4 & 0xFFFF0000u) == want) & ((v5 & 0xFFFF0000u) == want) &
                             ((v6 & 0xFFFF0000u) == want) & ((v7 & 0xFFFF0000u) == want);
                    }
                    if (fp) ok &= (ld_a(fp) >= fneed);
                    if (__all(ok)) break;
                }
                if (t > 0) {
                    const int ab = er * AS + 2 * up;
                    *(unsigned*)&A[ab + p0] = (v0 & 0xFFFFu) | (v1 << 16);
                    *(unsigned*)&A[ab + p1] = (v2 & 0xFFFFu) | (v3 << 16);
                    *(unsigned*)&A[ab + p2] = (v4 & 0xFFFFu) | (v5 << 16);
                    *(unsigned*)&A[ab + p3] = (v6 & 0xFFFFu) | (v7 << 16);
                }
            }
            __syncthreads();                       // B1 (drains t-1's global stores)
            if (tid == 0) st_a(FHown, (unsigned)t);

            unsigned q0, q1, q2, q3;
            if (l > 0) {
                const unsigned* zp = zinL + (size_t)(t & 15) * 12800 + er * 800 + 4 * (s * 40 + up);
                q0 = ld_a(zp); q1 = ld_a(zp + 1); q2 = ld_a(zp + 2); q3 = ld_a(zp + 3);
            }

            floatx4 a0 = {0, 0, 0, 0}, a1 = {0, 0, 0, 0};
            #pragma unroll
            for (int kt = 0; kt < 13; ++kt) {
                bf16x8 a = *(const bf16x8*)(&A[aoff + kt * 32]);
                a0 = __builtin_amdgcn_mfma_f32_16x16x32_bf16(a, breg[0][kt], a0, 0, 0, 0);
                a1 = __builtin_amdgcn_mfma_f32_16x16x32_bf16(a, breg[1][kt], a1, 0, 0, 0);
            }
            #pragma unroll
            for (int ri = 0; ri < 4; ++ri) {
                Z[(zr + ri) * ZS + zc0] = a0[ri];
                Z[(zr + ri) * ZS + zc0 + 16] = a1[ri];
            }
            __syncthreads();                       // B2

            float4 za = *(const float4*)(&Z[er * ZS + 8 * up]);
            float4 zb4 = *(const float4*)(&Z[er * ZS + 8 * up + 4]);
            if (l > 0) {
                za.x += bf_lo(q0); za.y += bf_hi(q0); za.z += bf_lo(q1); za.w += bf_hi(q1);
                zb4.x += bf_lo(q2); zb4.y += bf_hi(q2); zb4.z += bf_lo(q3); zb4.w += bf_hi(q3);
            }
            float iv = sigm_(za.x + pi0 * c0);
            float fv = sigm_(za.y + pf0 * c0);
            float cn = fv * c0 + iv * tanh_(za.z);
            float ov = sigm_(za.w + po0 * cn);
            float h0 = ov * tanh_(cn);
            c0 = cn;
            iv = sigm_(zb4.x + pi1 * c1);
            fv = sigm_(zb4.y + pf1 * c1);
            cn = fv * c1 + iv * tanh_(zb4.z);
            ov = sigm_(zb4.w + po1 * cn);
            float h1 = ov * tanh_(cn);
            c1 = cn;
            unsigned packh = (unsigned)f2bf(h0) | ((unsigned)f2bf(h1) << 16);
            *(unsigned*)&A[er * AS + ug0] = packh;
            if (l == 0 && tid < 16 && t + 1 < TSTEPS)
                *(uint2*)(&A[tid * AS + 400]) = *(const uint2*)(xpack + ((size_t)(t + 1) * 64 + g * 16 + tid) * 4);
            __syncthreads();                       // B3

            unsigned* hxs = hxL + (size_t)(t & 3) * 6400 + er * 400 + ug0;
            st_a(hxs, ((unsigned)t << 16) | (packh & 0xFFFFu));
            st_a(hxs + 1, ((unsigned)t << 16) | (packh >> 16));
            if (l < 2)
                st_a(ringL + (size_t)(t & 15) * 3200 + er * 200 + s * 40 + up, packh);
            else
                h2[(size_t)t * 12800 + (g * GB + er) * 200 + s * 40 + up] = packh;
        }
        __syncthreads();
        if (tid == 0) st_a(FHown, (unsigned)TSTEPS);
    } else {
        // ---------------- preGEMM block (2 steps per iter, stride 4, parity par) ----
        const int lz = plz;
        const int sp = psp;
        bf16x8 breg[2][13];
        #pragma unroll
        for (int n = 0; n < 2; ++n) {
            const unsigned short* bpp = Bpre + (size_t)lz * 1600 * KP
                + (size_t)(sp * CB + w * 32 + n * 16 + (lane & 15)) * KP + ((lane >> 4) << 3);
            #pragma unroll
            for (int kt = 0; kt < 13; ++kt) breg[n][kt] = *(const bf16x8*)(bpp + kt * 32);
        }
        const unsigned* ringS = hring + (size_t)(lz * NG + g) * RD * 3200;
        unsigned* zinD = zin + (size_t)(lz * NG + g) * RD * 12800;
        const unsigned* FHup = seqb + ((lz * NG + g) * NSL) * 16;
        const unsigned* FHdn = seqb + (((lz + 1) * NG + g) * NSL) * 16;
        unsigned* FZown = seqb + (60 + ((par * 2 + lz) * NG + g) * NSL + sp) * 16;
        const int cstart = par * 2;
        __syncthreads();

        for (int c = cstart; c < TSTEPS; c += 4) {
            {   // ballot poll: h availability + zin-ring backpressure
                const unsigned* fp = nullptr; unsigned need = 0;
                if (tid < NSL) { fp = FHup + tid * 16; need = (unsigned)(c + 2); }
                else if (tid < 2 * NSL) { fp = FHdn + (tid - NSL) * 16; need = (unsigned)(c > 14 ? c - 14 : 0); }
                bool ok = (fp == nullptr) || (ld_a(fp) >= need);
                while (!__all(ok)) { if (!ok) ok = ld_a(fp) >= need; }
            }
            __syncthreads();                       // B1 (drains prev iter's zin stores)
            if (tid == 0 && c > cstart) st_a(FZown, (unsigned)c);   // my-parity zin(<c) visible

            for (int i = tid; i < 6400; i += 640) {   // stage h(c),h(c+1)
                int tc = (i >= 3200) ? 1 : 0;
                int j = i - tc * 3200;
                unsigned v = ld_a(ringS + (size_t)((c + tc) & 15) * 3200 + j);
                int r = j / 200, d = j - r * 200;
                *(unsigned*)&A[(tc * 16 + r) * AS + 2 * d] = v;
            }
            if (tid < 32) {
                int tc = tid >> 4, r = tid & 15;
                *(uint2*)(&A[(tc * 16 + r) * AS + 400]) =
                    *(const uint2*)(xpack + ((size_t)(c + tc) * 64 + g * 16 + r) * 4);
            }
            __syncthreads();                       // B2

            floatx4 a00 = {0,0,0,0}, a01 = {0,0,0,0}, a10 = {0,0,0,0}, a11 = {0,0,0,0};
            #pragma unroll
            for (int kt = 0; kt < 13; ++kt) {
                bf16x8 x0 = *(const bf16x8*)(&A[aoff + kt * 32]);
                bf16x8 x1 = *(const bf16x8*)(&A[aoff + 16 * AS + kt * 32]);
                a00 = __builtin_amdgcn_mfma_f32_16x16x32_bf16(x0, breg[0][kt], a00, 0, 0, 0);
                a01 = __builtin_amdgcn_mfma_f32_16x16x32_bf16(x0, breg[1][kt], a01, 0, 0, 0);
                a10 = __builtin_amdgcn_mfma_f32_16x16x32_bf16(x1, breg[0][kt], a10, 0, 0, 0);
                a11 = __builtin_amdgcn_mfma_f32_16x16x32_bf16(x1, breg[1][kt], a11, 0, 0, 0);
            }
            #pragma unroll
            for (int m = 0; m < 2; ++m) {
                #pragma unroll
                for (int ri = 0; ri < 4; ++ri) {
                    Z[(zr + ri) * ZS + zc0] = (m ? a10[ri] : a00[ri]);
                    Z[(zr + ri) * ZS + zc0 + 16] = (m ? a11[ri] : a01[ri]);
                }
                __syncthreads();                   // Z ready
                float4 za = *(const float4*)(&Z[er * ZS + 8 * up]);
                float4 zbv = *(const float4*)(&Z[er * ZS + 8 * up + 4]);
                unsigned* zg = zinD + (size_t)((c + m) & 15) * 12800 + er * 800 + sp * 160 + 4 * up;
                st_a(zg,     (unsigned)f2bf(za.x) | ((unsigned)f2bf(za.y) << 16));
                st_a(zg + 1, (unsigned)f2bf(za.z) | ((unsigned)f2bf(za.w) << 16));
                st_a(zg + 2, (unsigned)f2bf(zbv.x) | ((unsigned)f2bf(zbv.y) << 16));
                st_a(zg + 3, (unsigned)f2bf(zbv.z) | ((unsigned)f2bf(zbv.w) << 16));
                __syncthreads();                   // pack reads done before Z reuse
            }
        }
        __syncthreads();
        if (tid == 0) st_a(FZown, (unsigned)TSTEPS);
    }
}

// ---- MDN head ------------------------------------------------------------
__global__ __launch_bounds__(256)
void mdn_kernel(const unsigned short* __restrict__ h2,
                const unsigned short* __restrict__ Bm,
                float* __restrict__ out) {
    const int blk = blockIdx.x;
    const int b = blk / 25;
    const int t0 = (blk - b * 25) * 32;
    const int tid = threadIdx.x;
    const int lane = tid & 63;
    const int w = tid >> 6;
    const int m = w & 1, nh = w >> 1;

    __shared__ unsigned short A[32 * 424];
    __shared__ float Z[32 * 132];
    __shared__ float rmax[32], rinv[32];

    for (int i = tid; i < 32 * 424; i += 256) A[i] = 0;
    __syncthreads();
    for (int c = tid; c < 32 * 50; c += 256) {
        int r = c / 50, j = c - r * 50;
        *(bf16x8*)(&A[r * 424 + j * 8]) = *(const bf16x8*)(h2 + (size_t)(t0 + r) * 25600 + b * 400 + j * 8);
    }
    if (tid < 32) A[tid * 424 + 400] = 0x3F80u;
    __syncthreads();

    floatx4 acc[4] = {{0,0,0,0},{0,0,0,0},{0,0,0,0},{0,0,0,0}};
    const int aoff = (m * 16 + (lane & 15)) * 424 + ((lane >> 4) << 3);
    #pragma unroll
    for (int kt = 0; kt < 13; ++kt) {
        bf16x8 a = *(const bf16x8*)(&A[aoff + kt * 32]);
        #pragma unroll
        for (int n = 0; n < 4; ++n) {
            const unsigned short* bp = Bm + (size_t)((nh * 4 + n) * 16 + (lane & 15)) * KP
                                          + ((lane >> 4) << 3) + kt * 32;
            acc[n] = __builtin_amdgcn_mfma_f32_16x16x32_bf16(a, *(const bf16x8*)bp, acc[n], 0, 0, 0);
        }
    }
    #pragma unroll
    for (int n = 0; n < 4; ++n) {
        int zc = (nh * 4 + n) * 16 + (lane & 15);
        int zrow = m * 16 + ((lane >> 4) << 2);
        #pragma unroll
        for (int ri = 0; ri < 4; ++ri)
            Z[(zrow + ri) * 132 + zc] = acc[n][ri];
    }
    __syncthreads();
    if (tid < 32) {
        float mx = -1e30f;
        for (int j = 0; j < 20; ++j) mx = fmaxf(mx, Z[tid * 132 + j]);
        float sm = 0.f;
        for (int j = 0; j < 20; ++j) sm += __expf(Z[tid * 132 + j] - mx);
        rmax[tid] = mx;
        rinv[tid] = 1.f / sm;
    }
    __syncthreads();
    for (int idxo = tid; idxo < 32 * 121; idxo += 256) {
        int r = idxo / 121, jo = idxo - r * 121;
        float v = Z[r * 132 + jo];
        float o;
        if (jo < 20) o = __expf(v - rmax[r]) * rinv[r];
        else if (jo < 60) o = v;
        else if (jo < 100) o = __expf(v);
        else if (jo < 120) o = tanh_(v);
        else o = sigm_(v);
        out[(size_t)(b * TSTEPS + t0 + r) * 121 + jo] = o;
    }
}

extern "C" void kernel_launch(void* const* d_in, const int* in_sizes, int n_in,
                              void* d_out, int out_size, void* d_ws, size_t ws_size,
                              hipStream_t stream) {
    const float* x = (const float*)d_in[0];
    const float* Wx[3] = {(const float*)d_in[1], (const float*)d_in[7], (const float*)d_in[13]};
    const float* Wh[3] = {(const float*)d_in[2], (const float*)d_in[8], (const float*)d_in[14]};
    const float* bb[3] = {(const float*)d_in[3], (const float*)d_in[9], (const float*)d_in[15]};
    Peeps pp;
    for (int l = 0; l < 3; ++l) {
        pp.pi[l] = (const float*)d_in[4 + 6 * l];
        pp.pf[l] = (const float*)d_in[5 + 6 * l];
        pp.po[l] = (const float*)d_in[6 + 6 * l];
    }
    const float* Wm = (const float*)d_in[19];
    const float* bm = (const float*)d_in[20];
    float* out = (float*)d_out;

    char* base = (char*)d_ws;
    size_t off = 0;
    auto alloc = [&](size_t bytes) -> void* {
        void* r = base + off;
        off = (off + bytes + 255) & ~(size_t)255;
        return r;
    };
    unsigned* seqb        = (unsigned*)alloc(4096 * sizeof(unsigned));              // 16 KB
    unsigned* hx          = (unsigned*)alloc((size_t)3 * NG * HXD * 6400 * 4);      // 1.23 MB
    unsigned* hring       = (unsigned*)alloc((size_t)3 * NG * RD * 3200 * 4);       // 2.46 MB
    unsigned* zin         = (unsigned*)alloc((size_t)2 * NG * RD * 12800 * 4);      // 6.55 MB
    unsigned short* Bp    = (unsigned short*)alloc((size_t)3 * 1600 * KP * 2);      // 4.0 MB
    unsigned short* Bpre  = (unsigned short*)alloc((size_t)2 * 1600 * KP * 2);      // 2.7 MB
    unsigned short* Bm    = (unsigned short*)alloc((size_t)128 * KP * 2);
    unsigned short* xpk   = (unsigned short*)alloc((size_t)TSTEPS * 64 * 4 * 2);
    unsigned short* h2    = (unsigned short*)alloc((size_t)TSTEPS * 64 * 400 * 2);  // 41 MB

    hipMemsetAsync(seqb, 0, 4096 * sizeof(unsigned), stream);
    hipMemsetAsync(hx, 0xAA, (size_t)3 * NG * HXD * 6400 * 4, stream);  // tags can't alias

    for (int l = 0; l < 3; ++l)
        pack_rec<<<2600, 256, 0, stream>>>(Wx[l], Wh[l], bb[l], Bp + (size_t)l * 1600 * KP, l == 0);
    pack_pre<<<2600, 256, 0, stream>>>(Wx[1], bb[1], Bpre);
    pack_pre<<<2600, 256, 0, stream>>>(Wx[2], bb[2], Bpre + (size_t)1600 * KP);
    pack_x<<<200, 256, 0, stream>>>(x, xpk);
    pack_mdn<<<208, 256, 0, stream>>>(Wm, bm, Bm);

    fused_scan<<<160, 640, 0, stream>>>(Bp, Bpre, xpk, hx, hring, zin, seqb,
                                        (unsigned*)h2, pp);

    mdn_kernel<<<1600, 256, 0, stream>>>(h2, Bm, out);
}